// Round 1
// baseline (410.187 us; speedup 1.0000x reference)
//
#include <hip/hip_runtime.h>
#include <math.h>

#define T_TOKENS 8192
#define NEXP 64
#define HID 2048
#define NITER 30
#define SINK_BLOCKS 32

// ---------------------------------------------------------------------------
// Kernel 1: router GEMM  logits[t][e] = sum_k A[t][k]*W[e][k]
// grid 512 x 256 threads. Tile: 16 tokens x 64 experts, BK=64, double-buffered.
// Also: writes sigmoid(logits) (affinities) and seeds sinkhorn partials with -1.
// ---------------------------------------------------------------------------
__global__ __launch_bounds__(256, 2)
void gemm_router_22995(const float* __restrict__ A, const float* __restrict__ W,
                       float* __restrict__ out, float* __restrict__ partials)
{
    __shared__ float Wl[2][64 * 64];   // [row][quad^swz] as float4 groups
    __shared__ float Al[2][16 * 64];
    const int tid  = threadIdx.x;
    const int bid  = blockIdx.x;
    const int wave = tid >> 6, lane = tid & 63;
    const int tok0 = bid * 16;

    // sentinel-init sinkhorn partial slots (30*32*64 floats): must be < 0
    {
        int gid = bid * 256 + tid;
        if (gid < NITER * SINK_BLOCKS * 64) partials[gid] = -1.0f;
    }

    float acc[4] = {0.f, 0.f, 0.f, 0.f};

    // stage chunk 0
    {
#pragma unroll
        for (int i = 0; i < 4; i++) {                  // W: 1024 float4 / 256 thr
            int f = i * 256 + tid; int r = f >> 4, q = f & 15;
            float4 v = *(const float4*)(W + (size_t)r * HID + q * 4);
            int qs = q ^ (r & 15);
            *(float4*)(&Wl[0][(r * 16 + qs) * 4]) = v;
        }
        int r = tid >> 4, q = tid & 15;                // A: 256 float4 / 256 thr
        float4 v = *(const float4*)(A + (size_t)(tok0 + r) * HID + q * 4);
        *(float4*)(&Al[0][r * 64 + q * 4]) = v;
    }
    __syncthreads();

    for (int c = 0; c < 32; ++c) {
        const int buf = c & 1;
        float4 wpre[4]; float4 apre;
        if (c < 31) {
            const int k0 = (c + 1) * 64;
#pragma unroll
            for (int i = 0; i < 4; i++) {
                int f = i * 256 + tid; int r = f >> 4, q = f & 15;
                wpre[i] = *(const float4*)(W + (size_t)r * HID + k0 + q * 4);
            }
            int r = tid >> 4, q = tid & 15;
            apre = *(const float4*)(A + (size_t)(tok0 + r) * HID + k0 + q * 4);
        }
#pragma unroll
        for (int k4 = 0; k4 < 16; ++k4) {
            float4 b = *(const float4*)(&Wl[buf][(lane * 16 + (k4 ^ (lane & 15))) * 4]);
#pragma unroll
            for (int i = 0; i < 4; i++) {
                float4 a = *(const float4*)(&Al[buf][(wave * 4 + i) * 64 + k4 * 4]);
                acc[i] = fmaf(a.x, b.x, acc[i]);
                acc[i] = fmaf(a.y, b.y, acc[i]);
                acc[i] = fmaf(a.z, b.z, acc[i]);
                acc[i] = fmaf(a.w, b.w, acc[i]);
            }
        }
        if (c < 31) {
            const int nbuf = buf ^ 1;
#pragma unroll
            for (int i = 0; i < 4; i++) {
                int f = i * 256 + tid; int r = f >> 4, q = f & 15;
                int qs = q ^ (r & 15);
                *(float4*)(&Wl[nbuf][(r * 16 + qs) * 4]) = wpre[i];
            }
            int r = tid >> 4, q = tid & 15;
            *(float4*)(&Al[nbuf][r * 64 + q * 4]) = apre;
        }
        __syncthreads();
    }

    // epilogue: logits + stable sigmoid
#pragma unroll
    for (int i = 0; i < 4; i++) {
        int t = tok0 + wave * 4 + i;
        float v = acc[i];
        out[(size_t)t * 64 + lane] = v;
        float s;
        if (v >= 0.f) { s = 1.0f / (1.0f + expf(-v)); }
        else          { float e = expf(v); s = e / (1.0f + e); }
        out[(size_t)T_TOKENS * 64 + (size_t)t * 64 + lane] = s;
    }
}

// ---------------------------------------------------------------------------
// Kernel 2: persistent sinkhorn. 32 blocks x 256 threads = 1 thread/token.
// Cost row (64 floats) lives in VGPRs. Cross-block sync: value-signaling
// (partials strictly > 0; sentinel/poison < 0), per-iteration slot buffers.
// ---------------------------------------------------------------------------
__global__ __launch_bounds__(256, 1)
void sinkhorn_router_22995(const float* __restrict__ logits,
                           float* __restrict__ out_idx,
                           float* __restrict__ partials)
{
    __shared__ float tile[4][64 * 68];   // per-wave transpose tile (padded)
    __shared__ float d1_lds[64];
    __shared__ float pl[4][64];
    const int tid  = threadIdx.x;
    const int bid  = blockIdx.x;
    const int wave = tid >> 6, lane = tid & 63;
    const int t    = bid * 256 + tid;    // token id

    float c[64];
#pragma unroll
    for (int e4 = 0; e4 < 16; e4++) {
        float4 v = *(const float4*)(logits + (size_t)t * 64 + e4 * 4);
        c[e4 * 4 + 0] = expf(v.x);
        c[e4 * 4 + 1] = expf(v.y);
        c[e4 * 4 + 2] = expf(v.z);
        c[e4 * 4 + 3] = expf(v.w);
    }
    if (tid < 64) d1_lds[tid] = 1.0f;
    __syncthreads();

    float d0 = 0.f;
    float* tw = tile[wave];

    for (int iter = 0; iter < NITER; ++iter) {
        // ---- phase 1: d0[t] = (1/T) / (sum_e d1[e]*c[e] + eps)
        float s = 0.f;
#pragma unroll
        for (int e4 = 0; e4 < 16; e4++) {
            float4 dv = *(const float4*)(&d1_lds[e4 * 4]);
            s = fmaf(c[e4 * 4 + 0], dv.x, s);
            s = fmaf(c[e4 * 4 + 1], dv.y, s);
            s = fmaf(c[e4 * 4 + 2], dv.z, s);
            s = fmaf(c[e4 * 4 + 3], dv.w, s);
        }
        d0 = (1.0f / 8192.0f) / (s + 1e-8f);

        // ---- phase 2: column sums of d0*c via per-wave LDS transpose
#pragma unroll
        for (int e4 = 0; e4 < 16; e4++) {
            float4 v;
            v.x = c[e4 * 4 + 0] * d0; v.y = c[e4 * 4 + 1] * d0;
            v.z = c[e4 * 4 + 2] * d0; v.w = c[e4 * 4 + 3] * d0;
            *(float4*)(&tw[lane * 68 + e4 * 4]) = v;
        }
        __syncthreads();
        float colsum = 0.f;
#pragma unroll 16
        for (int j = 0; j < 64; j++) colsum += tw[j * 68 + lane];
        pl[wave][lane] = colsum;
        __syncthreads();

        if (tid < 64) {
            float S = pl[0][tid] + pl[1][tid] + pl[2][tid] + pl[3][tid];
            __hip_atomic_store(&partials[(size_t)(iter * SINK_BLOCKS + bid) * 64 + tid], S,
                               __ATOMIC_RELAXED, __HIP_MEMORY_SCOPE_AGENT);
            // gather all 32 blocks' partials (pipelined loads, then re-poll laggards)
            float v[SINK_BLOCKS];
#pragma unroll
            for (int b = 0; b < SINK_BLOCKS; b++)
                v[b] = __hip_atomic_load(&partials[(size_t)(iter * SINK_BLOCKS + b) * 64 + tid],
                                         __ATOMIC_RELAXED, __HIP_MEMORY_SCOPE_AGENT);
            bool pending = true; int guard = 0;
            while (pending && guard++ < (1 << 22)) {
                pending = false;
#pragma unroll
                for (int b = 0; b < SINK_BLOCKS; b++) {
                    if (!(v[b] > 0.f)) {
                        v[b] = __hip_atomic_load(&partials[(size_t)(iter * SINK_BLOCKS + b) * 64 + tid],
                                                 __ATOMIC_RELAXED, __HIP_MEMORY_SCOPE_AGENT);
                        if (!(v[b] > 0.f)) pending = true;
                    }
                }
            }
            float S2 = 0.f;
#pragma unroll
            for (int b = 0; b < SINK_BLOCKS; b++) S2 += v[b];
            d1_lds[tid] = (1.0f / 64.0f) / (S2 + 1e-8f);
        }
        __syncthreads();
    }

    // ---- argmax_e of sinkroute = (d1[e]*c[e])*d0  (first max wins, like jnp.argmax)
    float best = -1.0f; int bi = 0;
#pragma unroll
    for (int e4 = 0; e4 < 16; e4++) {
        float4 dv = *(const float4*)(&d1_lds[e4 * 4]);
        float vv0 = (dv.x * c[e4 * 4 + 0]) * d0;
        float vv1 = (dv.y * c[e4 * 4 + 1]) * d0;
        float vv2 = (dv.z * c[e4 * 4 + 2]) * d0;
        float vv3 = (dv.w * c[e4 * 4 + 3]) * d0;
        if (vv0 > best) { best = vv0; bi = e4 * 4 + 0; }
        if (vv1 > best) { best = vv1; bi = e4 * 4 + 1; }
        if (vv2 > best) { best = vv2; bi = e4 * 4 + 2; }
        if (vv3 > best) { best = vv3; bi = e4 * 4 + 3; }
    }
    out_idx[t] = (float)bi;
}

extern "C" void kernel_launch(void* const* d_in, const int* in_sizes, int n_in,
                              void* d_out, int out_size, void* d_ws, size_t ws_size,
                              hipStream_t stream)
{
    const float* hs = (const float*)d_in[0];   // (4,2048,2048) fp32 -> 8192 x 2048
    const float* W  = (const float*)d_in[1];   // (64,2048) fp32
    float* out      = (float*)d_out;           // [logits | affinities | index-as-float]
    float* partials = (float*)d_ws;            // 30*32*64 floats

    gemm_router_22995<<<512, 256, 0, stream>>>(hs, W, out, partials);
    sinkhorn_router_22995<<<SINK_BLOCKS, 256, 0, stream>>>(
        out, out + (size_t)2 * T_TOKENS * NEXP, partials);
}